// Round 1
// baseline (783.255 us; speedup 1.0000x reference)
//
#include <hip/hip_runtime.h>
#include <hip/hip_bf16.h>

// ef = [P_src | P_tgt] gathered per edge; z = attn * (ef @ [Wa1|We]) + bias
// (attn scalar commutes past We). All GEMMs bf16 MFMA 16x16x32, fp32 accum.

typedef __bf16 bf16x8 __attribute__((ext_vector_type(8)));
typedef float f32x4 __attribute__((ext_vector_type(4)));

__device__ __forceinline__ unsigned short f2b(float f) {
    unsigned int u = __float_as_uint(f);
    unsigned int r = (u + 0x7fffu + ((u >> 16) & 1u)) >> 16;  // RNE
    return (unsigned short)r;
}

// ---- kernel 0: pack weights bf16, transposed to [n][k] for contiguous B-frags
__global__ __launch_bounds__(256) void pack_weights(
    const float* __restrict__ Ws, const float* __restrict__ Wt,
    const float* __restrict__ Wa1, const float* __restrict__ We,
    unsigned short* __restrict__ Wp1, unsigned short* __restrict__ Wp2)
{
    int id = blockIdx.x * 256 + threadIdx.x;
    if (id < 32768) {                      // Wp1[256][128]: [Ws|Wt] cols
        int n = id >> 7, k = id & 127;
        float v = (n < 128) ? Ws[k * 128 + n] : Wt[k * 128 + (n - 128)];
        Wp1[id] = f2b(v);
    }
    if (id < 98304) {                      // Wp2[384][256]: [Wa1|We] cols
        int n = id >> 8, k = id & 255;
        float v = (n < 128) ? Wa1[k * 128 + n] : We[k * 256 + (n - 128)];
        Wp2[id] = f2b(v);
    }
}

// ---- kernel 1: P[node][0:128]=emb@Ws+bs, P[node][128:256]=emb@Wt+bt (bf16)
__global__ __launch_bounds__(256) void node_proj(
    const float* __restrict__ emb, const unsigned short* __restrict__ Wp1,
    const float* __restrict__ bs, const float* __restrict__ bt,
    unsigned short* __restrict__ P, int NN)
{
    __shared__ unsigned short Alds[16][136];  // +8 pad: 2-way bank alias = free
    int t = threadIdx.x;
    {
        int row = t >> 4, cp = (t & 15) * 8;
        int node = blockIdx.x * 16 + row;
        if (node >= NN) node = NN - 1;
        const float* sp = emb + (size_t)node * 128 + cp;
        float4 v0 = *(const float4*)sp;
        float4 v1 = *(const float4*)(sp + 4);
        union { uint4 u; unsigned short s[8]; } pk;
        pk.s[0] = f2b(v0.x); pk.s[1] = f2b(v0.y); pk.s[2] = f2b(v0.z); pk.s[3] = f2b(v0.w);
        pk.s[4] = f2b(v1.x); pk.s[5] = f2b(v1.y); pk.s[6] = f2b(v1.z); pk.s[7] = f2b(v1.w);
        *(uint4*)&Alds[row][cp] = pk.u;
    }
    __syncthreads();
    int wv = t >> 6, lane = t & 63, n15 = lane & 15, quad = lane >> 4;
    f32x4 z4 = {0.f, 0.f, 0.f, 0.f};
    f32x4 acc[4] = {z4, z4, z4, z4};
    for (int ks = 0; ks < 4; ++ks) {
        bf16x8 a = *(const bf16x8*)&Alds[n15][ks * 32 + quad * 8];
#pragma unroll
        for (int tl = 0; tl < 4; ++tl) {
            int n = (wv * 4 + tl) * 16 + n15;
            bf16x8 b = *(const bf16x8*)(Wp1 + n * 128 + ks * 32 + quad * 8);
            acc[tl] = __builtin_amdgcn_mfma_f32_16x16x32_bf16(a, b, acc[tl], 0, 0, 0);
        }
    }
#pragma unroll
    for (int tl = 0; tl < 4; ++tl) {
        int c = (wv * 4 + tl) * 16 + n15;
        float bias = (c < 128) ? bs[c] : bt[c - 128];
#pragma unroll
        for (int r = 0; r < 4; ++r) {
            int node = blockIdx.x * 16 + quad * 4 + r;
            if (node < NN) P[(size_t)node * 256 + c] = f2b(acc[tl][r] + bias);
        }
    }
}

// ---- kernel 2: per-edge fused attn-gate + edge MLP + GeGLU + LayerNorm
__global__ __launch_bounds__(256) void edge_kernel(
    const int* __restrict__ eidx, const unsigned short* __restrict__ P,
    const unsigned short* __restrict__ Wp2,
    const float* __restrict__ ba1, const float* __restrict__ Wa2,
    const float* __restrict__ ba2, const float* __restrict__ be,
    const float* __restrict__ gamma, const float* __restrict__ beta,
    float* __restrict__ out, int E)
{
    __shared__ unsigned short Alds[64][264];  // 64 edges x 256 bf16 (+8 pad)
    __shared__ float Clds[16][392];           // 16 edges x 384 fp32 (+8 pad)
    int t = threadIdx.x;
    int base = blockIdx.x * 64;

    // stage ef tile: chunk c -> edge e=c>>5, part p=c&31; col offset = p*8
    // (p<16: src row of P, p>=16: tgt row; p*8 lands in [128,256) automatically)
#pragma unroll
    for (int i = 0; i < 8; ++i) {
        int c = t + i * 256;
        int e = c >> 5, p = c & 31;
        int ge = base + e; if (ge >= E) ge = E - 1;
        int node = (p < 16) ? eidx[ge] : eidx[E + ge];
        *(uint4*)&Alds[e][p * 8] = *(const uint4*)(P + (size_t)node * 256 + p * 8);
    }
    __syncthreads();

    int wv = t >> 6, lane = t & 63, n15 = lane & 15, quad = lane >> 4;
    f32x4 z4 = {0.f, 0.f, 0.f, 0.f};
    f32x4 acc[24];
#pragma unroll
    for (int i = 0; i < 24; ++i) acc[i] = z4;

    // wave wv owns col-tiles [6wv, 6wv+6) x all 4 M-tiles: B reused x4, A x6
    const unsigned short* wbase = Wp2 + (size_t)(wv * 96 + n15) * 256 + quad * 8;
    for (int ks = 0; ks < 8; ++ks) {
        bf16x8 a[4];
#pragma unroll
        for (int m = 0; m < 4; ++m)
            a[m] = *(const bf16x8*)&Alds[m * 16 + n15][ks * 32 + quad * 8];
#pragma unroll
        for (int n = 0; n < 6; ++n) {
            bf16x8 b = *(const bf16x8*)(wbase + n * 4096 + ks * 32);
#pragma unroll
            for (int m = 0; m < 4; ++m)
                acc[n * 4 + m] = __builtin_amdgcn_mfma_f32_16x16x32_bf16(a[m], b, acc[n * 4 + m], 0, 0, 0);
        }
    }

    // epilogue per M-tile: stage C to LDS, then 16 threads/edge row-wise
    int e16 = t >> 4, ci = t & 15;
    for (int mt = 0; mt < 4; ++mt) {
        __syncthreads();
#pragma unroll
        for (int n = 0; n < 6; ++n) {
            int ct = wv * 6 + n;
            f32x4 v = acc[n * 4 + mt];
#pragma unroll
            for (int r = 0; r < 4; ++r)
                Clds[quad * 4 + r][ct * 16 + n15] = v[r];
        }
        __syncthreads();
        // attn = sigmoid(relu(y[0:128]+ba1) . Wa2 + ba2)
        float part = 0.f;
#pragma unroll
        for (int j = 0; j < 8; ++j) {
            int c = ci * 8 + j;
            float h = fmaxf(Clds[e16][c] + ba1[c], 0.f);
            part = fmaf(h, Wa2[c], part);
        }
        part += __shfl_xor(part, 1); part += __shfl_xor(part, 2);
        part += __shfl_xor(part, 4); part += __shfl_xor(part, 8);
        float attn = 1.f / (1.f + expf(-(part + ba2[0])));
        // z = attn*y[128:384]+be; g = z_x * gelu_exact(z_gate); LN stats
        float g8[8], s1 = 0.f, s2 = 0.f;
#pragma unroll
        for (int j = 0; j < 8; ++j) {
            int c = ci * 8 + j;
            float zx = fmaf(attn, Clds[e16][128 + c], be[c]);
            float zg = fmaf(attn, Clds[e16][256 + c], be[128 + c]);
            float gv = zx * (0.5f * zg * (1.f + erff(zg * 0.70710678118f)));
            g8[j] = gv; s1 += gv; s2 = fmaf(gv, gv, s2);
        }
        s1 += __shfl_xor(s1, 1); s1 += __shfl_xor(s1, 2);
        s1 += __shfl_xor(s1, 4); s1 += __shfl_xor(s1, 8);
        s2 += __shfl_xor(s2, 1); s2 += __shfl_xor(s2, 2);
        s2 += __shfl_xor(s2, 4); s2 += __shfl_xor(s2, 8);
        float mu = s1 * 0.0078125f;
        float var = s2 * 0.0078125f - mu * mu;
        float rs = rsqrtf(var + 1e-5f);
        int edge = base + mt * 16 + e16;
        if (edge < E) {
            float* op = out + (size_t)edge * 128 + ci * 8;
#pragma unroll
            for (int j = 0; j < 8; ++j) {
                int c = ci * 8 + j;
                op[j] = (g8[j] - mu) * rs * gamma[c] + beta[c];
            }
        }
    }
}

extern "C" void kernel_launch(void* const* d_in, const int* in_sizes, int n_in,
                              void* d_out, int out_size, void* d_ws, size_t ws_size,
                              hipStream_t stream) {
    const float* emb  = (const float*)d_in[0];
    const int*   eidx = (const int*)d_in[1];
    const float* Ws   = (const float*)d_in[2];
    const float* bs   = (const float*)d_in[3];
    const float* Wt   = (const float*)d_in[4];
    const float* bt   = (const float*)d_in[5];
    const float* Wa1  = (const float*)d_in[6];
    const float* ba1  = (const float*)d_in[7];
    const float* Wa2  = (const float*)d_in[8];
    const float* ba2  = (const float*)d_in[9];
    const float* We   = (const float*)d_in[10];
    const float* be   = (const float*)d_in[11];
    const float* gam  = (const float*)d_in[12];
    const float* bet  = (const float*)d_in[13];
    float* out = (float*)d_out;
    int NN = in_sizes[0] / 128;
    int E  = in_sizes[1] / 2;
    unsigned short* Wp1 = (unsigned short*)d_ws;       // 64 KB
    unsigned short* Wp2 = Wp1 + 32768;                 // 192 KB
    unsigned short* P   = Wp2 + 98304;                 // 25.6 MB
    hipLaunchKernelGGL(pack_weights, dim3(384), dim3(256), 0, stream,
                       Ws, Wt, Wa1, We, Wp1, Wp2);
    hipLaunchKernelGGL(node_proj, dim3((NN + 15) / 16), dim3(256), 0, stream,
                       emb, Wp1, bs, bt, P, NN);
    hipLaunchKernelGGL(edge_kernel, dim3((E + 63) / 64), dim3(256), 0, stream,
                       eidx, P, Wp2, ba1, Wa2, ba2, be, gam, bet, out, E);
}